// Round 8
// baseline (68.987 us; speedup 1.0000x reference)
//
#include <hip/hip_runtime.h>

#define BLK 256
#define KJ 8                 // j's per thread -> JLANES = 2048 j's per block
#define JLANES (BLK * KJ)
#define ITILE 32             // i's per block (wave-uniform scalar loop)
#define IB 16                // i-batch for s_load_dwordx16 groups
#define GX (8192 / ITILE)    // 256
#define GY (8192 / JLANES)   // 4
#define NSLOTS (GX * GY)     // 1024 -> wait: 256*4 = 1024? no: 256*4=1024
// NSLOTS = 256 * 4 = 1024

__global__ __launch_bounds__(BLK) void svm_partial(
    const float* __restrict__ pred,
    const float2* __restrict__ tg,
    float* __restrict__ ws_rank,
    float* __restrict__ ws_reg,
    unsigned int* __restrict__ ws_cnt) {
  const int tid = threadIdx.x;
  const int i0 = blockIdx.x * ITILE;
  const int j0 = blockIdx.y * JLANES;

  // Per-lane j data: loaded once, lives in VGPRs (KJ=8 -> 16 VGPRs).
  float pj[KJ], tj[KJ];
  #pragma unroll
  for (int k = 0; k < KJ; ++k) {
    pj[k] = pred[j0 + tid + k * BLK];
    tj[k] = tg[j0 + tid + k * BLK].x;
  }

  float rank = 0.0f;
  unsigned int cnt = 0u;

  // i is wave-uniform: contiguous batches scalarize to s_load_dwordx16;
  // event check is a uniform scalar branch skipping ~half the i's.
  for (int ib = 0; ib < ITILE; ib += IB) {
    float pi[IB], ti[IB], ei[IB];
    #pragma unroll
    for (int u = 0; u < IB; ++u) {
      pi[u] = pred[i0 + ib + u];
      float2 te = tg[i0 + ib + u];
      ti[u] = te.x;
      ei[u] = te.y;
    }
    #pragma unroll
    for (int u = 0; u < IB; ++u) {
      if (ei[u] == 1.0f) {                 // uniform scalar branch
        const float pi1 = pi[u] + 1.0f;
        #pragma unroll
        for (int k = 0; k < KJ; ++k) {
          const bool m = tj[k] > ti[u];    // v_cmp -> vcc
          float h = fmaxf(pi1 - pj[k], 0.0f);
          h = m ? h : 0.0f;                // cndmask
          rank = fmaf(h, h, rank);
          cnt += m ? 1u : 0u;              // addc
        }
      }
    }
  }

  // Regression term: counted exactly once (y==0 slice, tid<ITILE).
  float reg = 0.0f;
  if (blockIdx.y == 0 && tid < ITILE) {
    const int i = i0 + tid;
    const float p = pred[i];
    const float2 te = tg[i];
    float d = p - te.x;
    if (te.y == 0.0f) d = fmaxf(d, 0.0f);
    reg = d * d;
  }

  // 64-lane shuffle reduction
  #pragma unroll
  for (int off = 32; off > 0; off >>= 1) {
    rank += __shfl_down(rank, off);
    reg  += __shfl_down(reg, off);
    cnt  += __shfl_down(cnt, off);
  }

  __shared__ float sr[BLK / 64];
  __shared__ float sg[BLK / 64];
  __shared__ unsigned int sc[BLK / 64];
  const int wave = tid >> 6;
  const int lane = tid & 63;
  if (lane == 0) { sr[wave] = rank; sg[wave] = reg; sc[wave] = cnt; }
  __syncthreads();

  if (tid == 0) {
    const int slot = blockIdx.y * GX + blockIdx.x;
    ws_rank[slot] = sr[0] + sr[1] + sr[2] + sr[3];
    ws_reg[slot]  = sg[0] + sg[1] + sg[2] + sg[3];
    ws_cnt[slot]  = sc[0] + sc[1] + sc[2] + sc[3];
  }
}

// Single wave: no barrier, minimal latency.
__global__ __launch_bounds__(64) void svm_finalize(
    const float* __restrict__ ws_rank,
    const float* __restrict__ ws_reg,
    const unsigned int* __restrict__ ws_cnt,
    float* __restrict__ out, int n, int nslots) {
  const int tid = threadIdx.x;
  double r = 0.0, g = 0.0;
  unsigned long long c = 0ull;
  for (int s = tid; s < nslots; s += 64) {
    r += (double)ws_rank[s];
    g += (double)ws_reg[s];
    c += (unsigned long long)ws_cnt[s];
  }
  #pragma unroll
  for (int off = 32; off > 0; off >>= 1) {
    r += __shfl_down(r, off);
    g += __shfl_down(g, off);
    c += __shfl_down(c, off);
  }
  if (tid == 0) {
    const double cd = (double)(c > 0ull ? c : 1ull);
    out[0] = (float)(0.5 * r / cd + 0.5 * g / (double)n);
  }
}

extern "C" void kernel_launch(void* const* d_in, const int* in_sizes, int n_in,
                              void* d_out, int out_size, void* d_ws, size_t ws_size,
                              hipStream_t stream) {
  const float* pred = (const float*)d_in[0];
  const float2* tg = (const float2*)d_in[1];
  float* out = (float*)d_out;
  const int n = in_sizes[0];  // 8192

  const int nslots = GX * GY;
  float* ws_rank = (float*)d_ws;
  float* ws_reg  = (float*)((char*)d_ws + nslots * sizeof(float));
  unsigned int* ws_cnt = (unsigned int*)((char*)d_ws + 2 * nslots * sizeof(float));

  svm_partial<<<dim3(GX, GY), BLK, 0, stream>>>(pred, tg, ws_rank, ws_reg, ws_cnt);
  svm_finalize<<<1, 64, 0, stream>>>(ws_rank, ws_reg, ws_cnt, out, n, nslots);
}

// Round 9
// 66.549 us; speedup vs baseline: 1.0366x; 1.0366x over previous
//
#include <hip/hip_runtime.h>

#define BLK 256
#define KJ 4                 // j's per thread -> JLANES = 1024 j's per block
#define JLANES (BLK * KJ)
#define ITILE 64             // i's per block (wave-uniform scalar loop)
#define IB 16                // i-batch for s_load_dwordx16 groups
#define GX (8192 / ITILE)    // 128
#define GY (8192 / JLANES)   // 8
#define NSLOTS (GX * GY)     // 1024 blocks, one float4 slot each

__global__ __launch_bounds__(BLK) void svm_partial(
    const float* __restrict__ pred,
    const float2* __restrict__ tg,
    float4* __restrict__ ws_slots) {
  const int tid = threadIdx.x;
  const int i0 = blockIdx.x * ITILE;
  const int j0 = blockIdx.y * JLANES;

  // Per-lane j data: loaded once, lives in VGPRs (KJ=4 -> 8 VGPRs).
  float pj[KJ], tj[KJ];
  #pragma unroll
  for (int k = 0; k < KJ; ++k) {
    pj[k] = pred[j0 + tid + k * BLK];
    tj[k] = tg[j0 + tid + k * BLK].x;
  }

  float rank = 0.0f;
  unsigned int cnt = 0u;     // wave-uniform: ballot/popcount path

  // i is wave-uniform: contiguous batches scalarize to s_load_dwordx16;
  // event check is a uniform scalar branch skipping ~half the i's.
  for (int ib = 0; ib < ITILE; ib += IB) {
    float pi[IB], ti[IB], ei[IB];
    #pragma unroll
    for (int u = 0; u < IB; ++u) {
      pi[u] = pred[i0 + ib + u];
      float2 te = tg[i0 + ib + u];
      ti[u] = te.x;
      ei[u] = te.y;
    }
    #pragma unroll
    for (int u = 0; u < IB; ++u) {
      if (ei[u] == 1.0f) {                 // uniform scalar branch
        const float pi1 = pi[u] + 1.0f;
        #pragma unroll
        for (int k = 0; k < KJ; ++k) {
          const bool m = tj[k] > ti[u];    // v_cmp -> mask
          cnt += (unsigned int)__popcll(__ballot(m));  // scalar pipe
          float h = fmaxf(pi1 - pj[k], 0.0f);
          h = m ? h : 0.0f;                // cndmask
          rank = fmaf(h, h, rank);
        }
      }
    }
  }

  // Regression term: counted exactly once (y==0 slice, tid<ITILE).
  float reg = 0.0f;
  if (blockIdx.y == 0 && tid < ITILE) {
    const int i = i0 + tid;
    const float p = pred[i];
    const float2 te = tg[i];
    float d = p - te.x;
    if (te.y == 0.0f) d = fmaxf(d, 0.0f);
    reg = d * d;
  }

  // 64-lane shuffle reduction (rank/reg only; cnt is wave-uniform)
  #pragma unroll
  for (int off = 32; off > 0; off >>= 1) {
    rank += __shfl_down(rank, off);
    reg  += __shfl_down(reg, off);
  }

  __shared__ float sr[BLK / 64];
  __shared__ float sg[BLK / 64];
  __shared__ unsigned int sc[BLK / 64];
  const int wave = tid >> 6;
  const int lane = tid & 63;
  if (lane == 0) { sr[wave] = rank; sg[wave] = reg; sc[wave] = cnt; }
  __syncthreads();

  if (tid == 0) {
    const float r = sr[0] + sr[1] + sr[2] + sr[3];
    const float g = sg[0] + sg[1] + sg[2] + sg[3];
    const unsigned int c = sc[0] + sc[1] + sc[2] + sc[3];
    // c <= ITILE*JLANES = 65536: exactly representable in float.
    const int slot = blockIdx.y * GX + blockIdx.x;
    ws_slots[slot] = make_float4(r, g, (float)c, 0.0f);  // one dwordx4 store
  }
}

// Single wave, no barrier; NSLOTS/64 = 16 dwordx4 loads per lane, pipelined.
__global__ __launch_bounds__(64) void svm_finalize(
    const float4* __restrict__ ws_slots,
    float* __restrict__ out, int n) {
  const int tid = threadIdx.x;
  double r = 0.0, g = 0.0, c = 0.0;
  #pragma unroll
  for (int s = tid; s < NSLOTS; s += 64) {
    const float4 v = ws_slots[s];
    r += (double)v.x;
    g += (double)v.y;
    c += (double)v.z;     // each term integral & exact
  }
  #pragma unroll
  for (int off = 32; off > 0; off >>= 1) {
    r += __shfl_down(r, off);
    g += __shfl_down(g, off);
    c += __shfl_down(c, off);
  }
  if (tid == 0) {
    const double cd = (c > 0.0 ? c : 1.0);
    out[0] = (float)(0.5 * r / cd + 0.5 * g / (double)n);
  }
}

extern "C" void kernel_launch(void* const* d_in, const int* in_sizes, int n_in,
                              void* d_out, int out_size, void* d_ws, size_t ws_size,
                              hipStream_t stream) {
  const float* pred = (const float*)d_in[0];
  const float2* tg = (const float2*)d_in[1];
  float* out = (float*)d_out;
  const int n = in_sizes[0];  // 8192

  float4* ws_slots = (float4*)d_ws;

  svm_partial<<<dim3(GX, GY), BLK, 0, stream>>>(pred, tg, ws_slots);
  svm_finalize<<<1, 64, 0, stream>>>(ws_slots, out, n);
}